// Round 7
// baseline (84.374 us; speedup 1.0000x reference)
//
#include <hip/hip_runtime.h>
#include <stdint.h>

#define NB   16
#define CIN  32
#define COUT 32
#define HH   256
#define WW   256
#define HWSZ (HH * WW)
#define EPSV 1e-5f
#define TWD  264     // LDS row words: zero pads at index 3 and 260, data at 4..259

typedef int v4i  __attribute__((ext_vector_type(4)));
typedef int v16i __attribute__((ext_vector_type(16)));

// ---------------------------------------------------------------------------
// Kernel 1 (tiny, 1 block): weight pack -> MFMA A-fragments + BN/correction
// tables. wb = sign(sign(w)+0.01): -1 iff w<0, +1 otherwise.
//   afrag[t*64+lane] = 16 i8 (+-1): o = lane&31, ch = (lane>>5)*16 + e
//   c0f[cls*32+o] = beta - mean*inv + Wsum[cls][o]*inv
//   c0f[288+o]    = -2 * gamma/sqrt(var+eps)   (c1, appended)
// B-matrix bit = signbit(x) (1 iff x<0), pads/invalid taps = 0. Then
//   conv = Wsum_valid - 2*acc  ->  result = acc*c1 + c0.
// ---------------------------------------------------------------------------
__global__ __launch_bounds__(288) void pack_w_kernel(
    const float* __restrict__ wt, const float* __restrict__ gamma,
    const float* __restrict__ beta, const float* __restrict__ rmean,
    const float* __restrict__ rvar, uint4* __restrict__ afrag,
    float* __restrict__ c0f) {
    __shared__ uint32_t pws[COUT * 9];
    const int j = threadIdx.x;                 // 0..287
    if (j < COUT * 9) {
        const int o = j / 9, t = j % 9;
        uint32_t bits = 0;
#pragma unroll
        for (int c = 0; c < CIN; ++c)
            bits |= (wt[(o * CIN + c) * 9 + t] < 0.f) ? (1u << c) : 0u;  // 1 = -1
        pws[j] = bits;
    }
    __syncthreads();
    if (j < 64) {
        const int sh = (j & 32) >> 1;          // channel half 0/16
#pragma unroll
        for (int t = 0; t < 9; ++t) {
            const uint32_t chunk = pws[(j & 31) * 9 + t] >> sh;
            uint32_t w[4];
#pragma unroll
            for (int k = 0; k < 4; ++k) {
                const uint32_t y = (((chunk >> (4 * k)) & 0xFu) * 0x204081u) & 0x01010101u;
                w[k] = (y * 0xFEu) | 0x01010101u;   // bit? 0xFF(-1) : 0x01(+1)
            }
            afrag[t * 64 + j] = make_uint4(w[0], w[1], w[2], w[3]);
        }
    }
    {
        const int cls = j >> 5;                // 0..8
        const int o   = j & 31;
        const int rc = cls / 3, cc = cls % 3;
        int wsum = 0;
#pragma unroll
        for (int dh = 0; dh < 3; ++dh)
#pragma unroll
            for (int dw = 0; dw < 3; ++dw) {
                const bool bad = (rc == 0 && dh == 0) || (rc == 2 && dh == 2) ||
                                 (cc == 0 && dw == 0) || (cc == 2 && dw == 2);
                if (!bad) wsum += 32 - 2 * __popc(pws[o * 9 + dh * 3 + dw]);
            }
        const float inv = gamma[o] * rsqrtf(rvar[o] + EPSV);
        c0f[cls * 32 + o] = beta[o] - rmean[o] * inv + (float)wsum * inv;
        if (cls == 0) c0f[288 + o] = -2.0f * inv;
    }
}

// ---------------------------------------------------------------------------
// Kernel 2: fused binarize + implicit-GEMM i8-MFMA conv + BN + ReLU.
// Block = (n, 2 output rows): 2048 blocks, 256 threads. Pack stages 4 rows
// (halo redundancy 2x instead of 3x), one uint4-quad task per thread
// (perfectly balanced). Conv: wave -> (row = wave>>1, 128-px segment =
// wave&1), two sequential passes of the 2-accumulator tap-outer inner loop
// (round-6 register footprint). A-fragments and BN tables are read directly
// from global (identical for all blocks -> L1-hot); LDS holds only the
// bit-packed tile (4.2 KB).
// ---------------------------------------------------------------------------
__global__ __launch_bounds__(256, 6) void biconv_mfma(
    const uint32_t* __restrict__ x, const uint4* __restrict__ afrag,
    const float* __restrict__ c0f, float* __restrict__ out) {
    const uint32_t bid = blockIdx.x;                       // 0..2047
    const uint32_t wg  = ((bid & 7u) << 8) | (bid >> 3);   // bijective XCD chunk
    const int n   = wg >> 7;                               // 0..15
    const int h0  = (wg & 127) << 1;                       // 0,2,...,254
    const int tid  = threadIdx.x;
    const int lane = tid & 63;
    const int wave = tid >> 6;

    __shared__ uint32_t tiles[4][TWD];

    if (tid < 8) tiles[tid >> 1][(tid & 1) ? 260 : 3] = 0u;

    // ---- pack 4 staged rows: r = tid>>6, quad q = tid&63 (1 task/thread) ----
    {
        const int r  = tid >> 6;
        const int q  = tid & 63;
        const int hr = h0 - 1 + r;                // -1 .. 256
        uint32_t b0 = 0, b1 = 0, b2 = 0, b3 = 0;
        if (hr >= 0 && hr < HH) {
            const uint32_t* xp = x + (size_t)n * (CIN * HWSZ) + (size_t)hr * WW + (q << 2);
#pragma unroll
            for (int c = 0; c < CIN; ++c) {
                const uint4 v = *reinterpret_cast<const uint4*>(xp + (size_t)c * HWSZ);
                b0 |= (v.x >> 31) << c;           // bit = signbit (x < 0)
                b1 |= (v.y >> 31) << c;
                b2 |= (v.z >> 31) << c;
                b3 |= (v.w >> 31) << c;
            }
        }
        *reinterpret_cast<uint4*>(&tiles[r][(q << 2) + 4]) = make_uint4(b0, b1, b2, b3);
    }
    __syncthreads();

    // ---- conv: wave = (row rsel, 128-px segment wseg); 2 passes x 2 accs ----
    const int l31  = lane & 31;
    const int shv  = (lane & 32) >> 1;     // channel half for B expansion
    const int og   = (lane >> 5) << 2;     // C/D row offset 0/4
    const int rsel = wave >> 1;            // output row within pair: 0/1
    const int wseg = (wave & 1) << 7;      // pixel segment base: 0/128

    const int h  = h0 + rsel;
    const int rc = (h == 0) ? 0 : ((h == HH - 1) ? 2 : 1);
    const float* c1 = c0f + 288;
    float* outn = out + (size_t)n * (COUT * HWSZ) + (size_t)h * WW;

#pragma unroll
    for (int p = 0; p < 2; ++p) {
        const int pA = wseg + (p << 6) + l31;   // tile A pixel
        const int pB = pA + 32;                 // tile B pixel
        v16i acc0 = {0}, acc1 = {0};
#pragma unroll
        for (int dh = 0; dh < 3; ++dh) {
            const uint32_t* trow = &tiles[rsel + dh][0];
#pragma unroll
            for (int dw = 0; dw < 3; ++dw) {
                const v4i a = *reinterpret_cast<const v4i*>(&afrag[(dh * 3 + dw) * 64 + lane]);
                const uint32_t hA = trow[pA + 3 + dw] >> shv;
                const uint32_t hB = trow[pB + 3 + dw] >> shv;
                v4i b;
                b.x = (int)((( hA        & 0xFu) * 0x204081u) & 0x01010101u);
                b.y = (int)((((hA >> 4)  & 0xFu) * 0x204081u) & 0x01010101u);
                b.z = (int)((((hA >> 8)  & 0xFu) * 0x204081u) & 0x01010101u);
                b.w = (int)((((hA >> 12) & 0xFu) * 0x204081u) & 0x01010101u);
                acc0 = __builtin_amdgcn_mfma_i32_32x32x32_i8(a, b, acc0, 0, 0, 0);
                b.x = (int)((( hB        & 0xFu) * 0x204081u) & 0x01010101u);
                b.y = (int)((((hB >> 4)  & 0xFu) * 0x204081u) & 0x01010101u);
                b.z = (int)((((hB >> 8)  & 0xFu) * 0x204081u) & 0x01010101u);
                b.w = (int)((((hB >> 12) & 0xFu) * 0x204081u) & 0x01010101u);
                acc1 = __builtin_amdgcn_mfma_i32_32x32x32_i8(a, b, acc1, 0, 0, 0);
            }
        }
        // ---- epilogue: C/D row = (e&3)+8*(e>>2)+og, col = pixel ----
        const int ccA = (pA == 0) ? 0 : ((pA == WW - 1) ? 2 : 1);
        const int ccB = (pB == WW - 1) ? 2 : 1;       // pB >= 32, never 0
        const float* c0A = c0f + (rc * 3 + ccA) * 32;
        const float* c0B = c0f + (rc * 3 + ccB) * 32;
#pragma unroll
        for (int e = 0; e < 16; ++e) {
            const int o = (e & 3) + ((e >> 2) << 3) + og;
            const float vA = fmaf((float)acc0[e], c1[o], c0A[o]);
            const float vB = fmaf((float)acc1[e], c1[o], c0B[o]);
            __builtin_nontemporal_store(vA > 0.f ? vA : 0.f, outn + (size_t)o * HWSZ + pA);
            __builtin_nontemporal_store(vB > 0.f ? vB : 0.f, outn + (size_t)o * HWSZ + pB);
        }
    }
}

// ---------------------------------------------------------------------------
extern "C" void kernel_launch(void* const* d_in, const int* in_sizes, int n_in,
                              void* d_out, int out_size, void* d_ws, size_t ws_size,
                              hipStream_t stream) {
    const float* x     = (const float*)d_in[0];
    const float* wt    = (const float*)d_in[1];
    const float* gamma = (const float*)d_in[2];
    const float* beta  = (const float*)d_in[3];
    const float* rmean = (const float*)d_in[4];
    const float* rvar  = (const float*)d_in[5];
    float* out = (float*)d_out;

    uint4* afrag = (uint4*)d_ws;                           // 9*64*16 = 9216 B
    float* c0f   = (float*)((char*)d_ws + 9216);           // 288 + 32 floats

    pack_w_kernel<<<dim3(1), dim3(288), 0, stream>>>(wt, gamma, beta, rmean,
                                                     rvar, afrag, c0f);
    biconv_mfma<<<dim3(NB * HH / 2), dim3(256), 0, stream>>>(
        (const uint32_t*)x, afrag, c0f, out);
}

// Round 8
// 49.826 us; speedup vs baseline: 1.6934x; 1.6934x over previous
//
#include <hip/hip_runtime.h>
#include <stdint.h>

#define NB   16
#define CIN  32
#define COUT 32
#define HH   256
#define WW   256
#define HWSZ (HH * WW)
#define EPSV 1e-5f
#define TWD  264     // LDS row words: zero pads at index 3 and 260, data at 4..259

typedef int v4i  __attribute__((ext_vector_type(4)));
typedef int v16i __attribute__((ext_vector_type(16)));

// ---------------------------------------------------------------------------
// Kernel 1 (tiny, 1 block): weight pack -> MFMA A-fragments + BN/correction
// tables. wb = sign(sign(w)+0.01): -1 iff w<0, +1 otherwise.
//   afrag[t*64+lane] = 16 i8 (+-1): o = lane&31, ch = (lane>>5)*16 + e
//   c0f[cls*32+o] = beta - mean*inv + Wsum[cls][o]*inv
//   c0f[288+o]    = -2 * gamma/sqrt(var+eps)   (c1, appended)
// B-matrix bit = signbit(x) (1 iff x<0), pads/invalid taps = 0. Then
//   conv = Wsum_valid - 2*acc  ->  result = acc*c1 + c0.
// ---------------------------------------------------------------------------
__global__ __launch_bounds__(288) void pack_w_kernel(
    const float* __restrict__ wt, const float* __restrict__ gamma,
    const float* __restrict__ beta, const float* __restrict__ rmean,
    const float* __restrict__ rvar, uint4* __restrict__ afrag,
    float* __restrict__ c0f) {
    __shared__ uint32_t pws[COUT * 9];
    const int j = threadIdx.x;                 // 0..287
    if (j < COUT * 9) {
        const int o = j / 9, t = j % 9;
        uint32_t bits = 0;
#pragma unroll
        for (int c = 0; c < CIN; ++c)
            bits |= (wt[(o * CIN + c) * 9 + t] < 0.f) ? (1u << c) : 0u;  // 1 = -1
        pws[j] = bits;
    }
    __syncthreads();
    if (j < 64) {
        const int sh = (j & 32) >> 1;          // channel half 0/16
#pragma unroll
        for (int t = 0; t < 9; ++t) {
            const uint32_t chunk = pws[(j & 31) * 9 + t] >> sh;
            uint32_t w[4];
#pragma unroll
            for (int k = 0; k < 4; ++k) {
                const uint32_t y = (((chunk >> (4 * k)) & 0xFu) * 0x204081u) & 0x01010101u;
                w[k] = (y * 0xFEu) | 0x01010101u;   // bit? 0xFF(-1) : 0x01(+1)
            }
            afrag[t * 64 + j] = make_uint4(w[0], w[1], w[2], w[3]);
        }
    }
    {
        const int cls = j >> 5;                // 0..8
        const int o   = j & 31;
        const int rc = cls / 3, cc = cls % 3;
        int wsum = 0;
#pragma unroll
        for (int dh = 0; dh < 3; ++dh)
#pragma unroll
            for (int dw = 0; dw < 3; ++dw) {
                const bool bad = (rc == 0 && dh == 0) || (rc == 2 && dh == 2) ||
                                 (cc == 0 && dw == 0) || (cc == 2 && dw == 2);
                if (!bad) wsum += 32 - 2 * __popc(pws[o * 9 + dh * 3 + dw]);
            }
        const float inv = gamma[o] * rsqrtf(rvar[o] + EPSV);
        c0f[cls * 32 + o] = beta[o] - rmean[o] * inv + (float)wsum * inv;
        if (cls == 0) c0f[288 + o] = -2.0f * inv;
    }
}

// ---------------------------------------------------------------------------
// Kernel 2: fused binarize + implicit-GEMM i8-MFMA conv + BN + ReLU.
// Round-6 structure with ONE change: 2 output rows per block, 512 threads
// (2048 blocks — same total wave count as round 6). Threads 0..255 pack the
// 4 staged rows (bit = signbit(x), uint4 loads, 1 quad-task each); threads
// 256..511 stage A-fragments + BN tables into LDS. Conv: 8 waves, wave =
// (row rsel = wave>>2, 64-px segment = wave&3), identical 2-accumulator
// tap-outer inner loop as round 6 (single pass per wave).
// ---------------------------------------------------------------------------
__global__ __launch_bounds__(512) void biconv_mfma(
    const uint32_t* __restrict__ x, const uint4* __restrict__ afrag,
    const float* __restrict__ c0f, float* __restrict__ out) {
    const uint32_t bid = blockIdx.x;                       // 0..2047
    const uint32_t wg  = ((bid & 7u) << 8) | (bid >> 3);   // bijective XCD chunk
    const int n   = wg >> 7;                               // 0..15
    const int h0  = (wg & 127) << 1;                       // 0,2,...,254
    const int tid  = threadIdx.x;
    const int lane = tid & 63;
    const int wave = tid >> 6;

    __shared__ uint32_t tiles[4][TWD];
    __shared__ uint4    afsh[9 * 64];     // 9216 B
    __shared__ float    csh[320];         // c0[0..287], c1[288..319]

    if (tid < 256) {
        // ---- pack 4 staged rows: r = tid>>6, quad q = tid&63 ----
        const int r  = tid >> 6;
        const int q  = tid & 63;
        const int hr = h0 - 1 + r;                // -1 .. 256
        uint32_t b0 = 0, b1 = 0, b2 = 0, b3 = 0;
        if (hr >= 0 && hr < HH) {
            const uint32_t* xp = x + (size_t)n * (CIN * HWSZ) + (size_t)hr * WW + (q << 2);
#pragma unroll
            for (int c = 0; c < CIN; ++c) {
                const uint4 v = *reinterpret_cast<const uint4*>(xp + (size_t)c * HWSZ);
                b0 |= (v.x >> 31) << c;           // bit = signbit (x < 0)
                b1 |= (v.y >> 31) << c;
                b2 |= (v.z >> 31) << c;
                b3 |= (v.w >> 31) << c;
            }
        }
        *reinterpret_cast<uint4*>(&tiles[r][(q << 2) + 4]) = make_uint4(b0, b1, b2, b3);
    } else {
        const int t2 = tid - 256;          // 0..255
        afsh[t2]       = afrag[t2];
        afsh[t2 + 256] = afrag[t2 + 256];
        if (t2 < 64)  afsh[t2 + 512] = afrag[t2 + 512];    // 576 total
        csh[t2] = c0f[t2];
        if (t2 < 64)  csh[t2 + 256] = c0f[t2 + 256];       // 320 total
        if (t2 < 8)   tiles[t2 >> 1][(t2 & 1) ? 260 : 3] = 0u;
    }
    __syncthreads();

    // ---- conv: wave = (row rsel, 64-px segment); 2 accumulator tiles ----
    const int l31  = lane & 31;
    const int shv  = (lane & 32) >> 1;     // channel half for B expansion
    const int og   = (lane >> 5) << 2;     // C/D row offset 0/4
    const int rsel = wave >> 2;            // output row within pair: 0/1
    const int pA   = ((wave & 3) << 6) + l31;   // tile A pixel
    const int pB   = pA + 32;                   // tile B pixel

    const int h  = h0 + rsel;
    const int rc = (h == 0) ? 0 : ((h == HH - 1) ? 2 : 1);

    v16i acc0 = {0}, acc1 = {0};
#pragma unroll
    for (int dh = 0; dh < 3; ++dh) {
        const uint32_t* trow = &tiles[rsel + dh][0];
#pragma unroll
        for (int dw = 0; dw < 3; ++dw) {
            const v4i a = *reinterpret_cast<const v4i*>(&afsh[(dh * 3 + dw) * 64 + lane]);
            const uint32_t hA = trow[pA + 3 + dw] >> shv;
            const uint32_t hB = trow[pB + 3 + dw] >> shv;
            v4i b;
            b.x = (int)((( hA        & 0xFu) * 0x204081u) & 0x01010101u);
            b.y = (int)((((hA >> 4)  & 0xFu) * 0x204081u) & 0x01010101u);
            b.z = (int)((((hA >> 8)  & 0xFu) * 0x204081u) & 0x01010101u);
            b.w = (int)((((hA >> 12) & 0xFu) * 0x204081u) & 0x01010101u);
            acc0 = __builtin_amdgcn_mfma_i32_32x32x32_i8(a, b, acc0, 0, 0, 0);
            b.x = (int)((( hB        & 0xFu) * 0x204081u) & 0x01010101u);
            b.y = (int)((((hB >> 4)  & 0xFu) * 0x204081u) & 0x01010101u);
            b.z = (int)((((hB >> 8)  & 0xFu) * 0x204081u) & 0x01010101u);
            b.w = (int)((((hB >> 12) & 0xFu) * 0x204081u) & 0x01010101u);
            acc1 = __builtin_amdgcn_mfma_i32_32x32x32_i8(a, b, acc1, 0, 0, 0);
        }
    }

    // ---- epilogue: C/D row = (e&3)+8*(e>>2)+og, col = pixel ----
    const int ccA = (pA == 0) ? 0 : ((pA == WW - 1) ? 2 : 1);
    const int ccB = (pB == WW - 1) ? 2 : 1;       // pB >= 32, never 0
    const float* c0A = &csh[(rc * 3 + ccA) * 32];
    const float* c0B = &csh[(rc * 3 + ccB) * 32];
    const float* c1  = &csh[288];
    float* outn = out + (size_t)n * (COUT * HWSZ) + (size_t)h * WW;
#pragma unroll
    for (int e = 0; e < 16; ++e) {
        const int o = (e & 3) + ((e >> 2) << 3) + og;
        const float vA = fmaf((float)acc0[e], c1[o], c0A[o]);
        const float vB = fmaf((float)acc1[e], c1[o], c0B[o]);
        __builtin_nontemporal_store(vA > 0.f ? vA : 0.f, outn + (size_t)o * HWSZ + pA);
        __builtin_nontemporal_store(vB > 0.f ? vB : 0.f, outn + (size_t)o * HWSZ + pB);
    }
}

// ---------------------------------------------------------------------------
extern "C" void kernel_launch(void* const* d_in, const int* in_sizes, int n_in,
                              void* d_out, int out_size, void* d_ws, size_t ws_size,
                              hipStream_t stream) {
    const float* x     = (const float*)d_in[0];
    const float* wt    = (const float*)d_in[1];
    const float* gamma = (const float*)d_in[2];
    const float* beta  = (const float*)d_in[3];
    const float* rmean = (const float*)d_in[4];
    const float* rvar  = (const float*)d_in[5];
    float* out = (float*)d_out;

    uint4* afrag = (uint4*)d_ws;                           // 9*64*16 = 9216 B
    float* c0f   = (float*)((char*)d_ws + 9216);           // 288 + 32 floats

    pack_w_kernel<<<dim3(1), dim3(288), 0, stream>>>(wt, gamma, beta, rmean,
                                                     rvar, afrag, c0f);
    biconv_mfma<<<dim3(NB * HH / 2), dim3(512), 0, stream>>>(
        (const uint32_t*)x, afrag, c0f, out);
}